// Round 8
// baseline (147.156 us; speedup 1.0000x reference)
//
#include <hip/hip_runtime.h>
#include <math.h>

#define NSTEP 10
// per-block (one wave) LDS tile: 32 samples x 60 f32, pred then gt. 15360 B.
#define TILE_DW   3840          // total dwords per tile buffer
#define GT_DW     1920          // gt half starts here
#define TILES_PER_BLOCK 4

#define GV (const __attribute__((address_space(1))) void*)
#define LV (__attribute__((address_space(3))) void*)

// ---- crude atan2: 3-term minimax, max err ~6e-4 rad (rot terms are ~1e-5 of loss).
__device__ __forceinline__ float fast_atan2f(float y, float x) {
    float ax = fabsf(x), ay = fabsf(y);
    float mx = fmaxf(ax, ay);
    float mn = fminf(ax, ay);
    float a = mn * __builtin_amdgcn_rcpf(mx);
    float s = a * a;
    float r = fmaf(s, fmaf(s, 0.0793312f, -0.2886793f), 0.9953545f) * a;
    if (ay > ax) r = 1.57079632679f - r;
    if (x < 0.0f) r = 3.14159265359f - r;
    return copysignf(r, y);
}

// R5 layout: [0]=R00=cz*cy [1]=R10=sz*cy [2]=R20=-sy [3]=R21=cy*sx [4]=R22=cy*cx
__device__ __forceinline__ void euler2mat5(float x, float y, float z, float R[5]) {
    float sx, cx, sy, cy, sz, cz;
    __sincosf(x, &sx, &cx);
    __sincosf(y, &sy, &cy);
    __sincosf(z, &sz, &cz);
    R[0] = cz * cy;
    R[1] = sz * cy;
    R[2] = -sy;
    R[3] = cy * sx;
    R[4] = cy * cx;
}

// diff against partner lane (pred<->gt) via DPP quad_perm [1,0,3,2] — pure VALU
__device__ __forceinline__ void emit(float v, float& acc) {
    int pi = __builtin_amdgcn_update_dpp(0, __float_as_int(v), 0xB1, 0xF, 0xF, true);
    float d = v - __int_as_float(pi);
    acc = fmaf(d, d, acc);
}

__device__ __forceinline__ void emit_euler(const float M[5], float& acc) {
    float sy = __builtin_amdgcn_sqrtf(fmaf(M[0], M[0], M[1] * M[1]));
    emit(fast_atan2f(M[3], M[4]), acc);   // x = atan2(M21, M22)
    emit(fast_atan2f(-M[2], sy), acc);    // y = atan2(-M20, sy)
    emit(fast_atan2f(M[1], M[0]), acc);   // z = atan2(M10, M00)
}

// 15 x (64 lanes x 16 B) DMA, no VGPR destination -> cannot be re-batched by
// the register allocator. Instruction 7 straddles pred-tail/gt-head via
// per-lane source select (global addr is per-lane; LDS dest is linear).
__device__ __forceinline__ void stage_tile(
    float* dst, const float* pg, const float* gg, int lane)
{
    #pragma unroll
    for (int it = 0; it < 15; ++it) {
        const int d = it * 256 + lane * 4;      // dword index in tile
        const float* src = (d < GT_DW) ? (pg + d) : (gg + (d - GT_DW));
        __builtin_amdgcn_global_load_lds(GV src, LV(dst + it * 256), 16, 0, 0);
    }
}

// R7-verified compute body for one 32-sample tile (lane pair = pred/gt).
__device__ __forceinline__ void compute_tile(const float* lds_, int lane, float& acc)
{
    const float* row = lds_ + ((lane & 1) ? GT_DW : 0) + (lane >> 1) * 60;

    float v[3], cac[3] = {0,0,0}, tprev[3];
    float Q[5];

    // ---- chunk 0 (steps 0,1): floats [0,12) ----
    float4 A = *reinterpret_cast<const float4*>(row);
    float4 B = *reinterpret_cast<const float4*>(row + 4);
    float4 C = *reinterpret_cast<const float4*>(row + 8);
    float e0 = A.x, e1 = A.y, e2 = A.z, e3 = A.w,
          e4 = B.x, e5 = B.y, e6 = B.z, e7 = B.w,
          e8 = C.x, e9 = C.y, e10 = C.z, e11 = C.w;

    v[0] = e0; v[1] = e1; v[2] = e2;
    emit(v[0], acc); emit(v[1], acc); emit(v[2], acc);
    #pragma unroll
    for (int k = 0; k < 3; ++k) { v[k] *= 2.0f; emit(v[k], acc); }
    tprev[0] = e6; tprev[1] = e7; tprev[2] = e8;

    {
        float R1[5];
        euler2mat5(e3, e4, e5, Q);          // Q = R0
        euler2mat5(e9, e10, e11, R1);       // R1
        emit_euler(R1, acc);                // step 0: M = R1
        #pragma unroll
        for (int k = 0; k < 5; ++k) Q[k] *= R1[k];   // Q = R1 (.) R0
        emit_euler(Q, acc);                 // step 1
        #pragma unroll
        for (int k = 0; k < 5; ++k) Q[k] *= R1[k];   // fold in R1 for P_2
    }

    // ---- chunks 1..4 (steps 2c, 2c+1): floats [12c, 12c+12) ----
    #pragma unroll
    for (int c = 1; c < 5; ++c) {
        const float* rc = row + 12 * c;
        float4 FA = *reinterpret_cast<const float4*>(rc);
        float4 FB = *reinterpret_cast<const float4*>(rc + 4);
        float4 FC = *reinterpret_cast<const float4*>(rc + 8);
        float f0 = FA.x, f1 = FA.y, f2 = FA.z, f3 = FA.w,
              f4 = FB.x, f5 = FB.y, f6 = FB.z, f7 = FB.w,
              f8 = FC.x, f9 = FC.y, f10 = FC.z, f11 = FC.w;

        // translation step 2c: cac += t_{2c-1}; v = 2v + cac
        cac[0] += tprev[0]; cac[1] += tprev[1]; cac[2] += tprev[2];
        #pragma unroll
        for (int k = 0; k < 3; ++k) { v[k] = fmaf(2.0f, v[k], cac[k]); emit(v[k], acc); }
        // translation step 2c+1: cac += t_{2c}; v = 2v + cac
        cac[0] += f0; cac[1] += f1; cac[2] += f2;
        #pragma unroll
        for (int k = 0; k < 3; ++k) { v[k] = fmaf(2.0f, v[k], cac[k]); emit(v[k], acc); }
        tprev[0] = f6; tprev[1] = f7; tprev[2] = f8;

        // rotation step 2c: M = Q
        emit_euler(Q, acc);
        {
            float R[5];
            euler2mat5(f3, f4, f5, R);      // R_{2c}
            #pragma unroll
            for (int k = 0; k < 5; ++k) Q[k] *= R[k];
        }
        // rotation step 2c+1
        emit_euler(Q, acc);
        if (c < 4) {
            float R[5];
            euler2mat5(f9, f10, f11, R);    // R_{2c+1}
            #pragma unroll
            for (int k = 0; k < 5; ++k) Q[k] *= R[k];
        }
    }
}

// Persistent 1-wave blocks: 2048 blocks (8/CU), each owns 4 CONSECUTIVE
// 32-sample tiles. Per tile: wait DMA -> compute -> issue next tile's DMA.
// The next tile's fill latency is covered by the other 7 waves on the CU
// (TLP), and blocks are dispatched once (no CP-starvation / re-ramp, which
// R7 showed: only 6.4 of 10 configured waves resident with 8192 short
// blocks). Compute + staging bodies are byte-identical to R7.
__global__ __launch_bounds__(64, 2) void cycle_loss_main(
    const float* __restrict__ pred, const float* __restrict__ gt,
    float* __restrict__ partial)
{
    __shared__ float lds[TILE_DW];
    const int lane = threadIdx.x;        // 64-thread block == one wave

    const size_t base0 = (size_t)blockIdx.x * TILES_PER_BLOCK * 32 * 60;
    const float* pg = pred + base0;
    const float* gg = gt   + base0;

    float acc = 0.0f;

    stage_tile(lds, pg, gg, lane);

    #pragma unroll
    for (int i = 0; i < TILES_PER_BLOCK; ++i) {
        asm volatile("s_waitcnt vmcnt(0)" ::: "memory");
        __builtin_amdgcn_sched_barrier(0);

        compute_tile(lds, lane, acc);

        if (i < TILES_PER_BLOCK - 1) {
            // all ds_reads of this tile are consumed by now; fence them
            // against the DMA overwrite, then issue next tile's fill.
            asm volatile("s_waitcnt lgkmcnt(0)" ::: "memory");
            __builtin_amdgcn_sched_barrier(0);
            stage_tile(lds, pg + (size_t)(i + 1) * 1920,
                            gg + (size_t)(i + 1) * 1920, lane);
        }
    }

    // ---- reduction: wave shuffle -> one float partial per block (no barrier) ----
    #pragma unroll
    for (int off = 32; off > 0; off >>= 1)
        acc += __shfl_down(acc, off, 64);
    if (lane == 0)
        partial[blockIdx.x] = acc;
}

__global__ __launch_bounds__(256) void cycle_loss_fin(
    const float* __restrict__ partial, float* __restrict__ out,
    int nparts, float inv)
{
    int t = threadIdx.x;
    float s = 0.0f;
    for (int i = t; i < nparts; i += 256) s += partial[i];
    int lane = t & 63, wid = t >> 6;
    #pragma unroll
    for (int off = 32; off > 0; off >>= 1)
        s += __shfl_down(s, off, 64);
    __shared__ float warp_s[4];
    if (lane == 0) warp_s[wid] = s;
    __syncthreads();
    if (t == 0)
        out[0] = (warp_s[0] + warp_s[1] + warp_s[2] + warp_s[3]) * inv;
}

extern "C" void kernel_launch(void* const* d_in, const int* in_sizes, int n_in,
                              void* d_out, int out_size, void* d_ws, size_t ws_size,
                              hipStream_t stream) {
    const float* pred = (const float*)d_in[0];
    const float* gt   = (const float*)d_in[1];
    int batch = in_sizes[0] / 60;
    float* partial = (float*)d_ws;

    const int blocks = batch / (32 * TILES_PER_BLOCK);   // 262144/128 = 2048
    cycle_loss_main<<<blocks, 64, 0, stream>>>(pred, gt, partial);

    // each d^2 counted twice (both lanes of a pair) -> extra 0.5
    double inv = 0.5 / (60.0 * (double)batch * (double)batch);
    cycle_loss_fin<<<1, 256, 0, stream>>>(partial, (float*)d_out, blocks, (float)inv);
}